// Round 1
// baseline (304.085 us; speedup 1.0000x reference)
//
#include <hip/hip_runtime.h>
#include <math.h>

#define BBATCH 64
#define LL 200
#define DD 300
#define PP 16
#define EPSV 1e-12f
#define KG 320          // global K-pad (10 chunks of 32)
#define PS 328          // maxsim LDS row stride in halfs (656 B: 4-bank row shift)
#define NCH 10
#define SRS 308         // prep LDS row stride in f32: 308 mod 32 = 12 -> 8-row groups hit all 32 banks

typedef _Float16 f16x8 __attribute__((ext_vector_type(8)));
typedef float f32x4v __attribute__((ext_vector_type(4)));

// ---------------- prep: norms + f16 conversion + ksq frag table --------------------------
// grid (7, 2, 64), block 256. 32 rows/block. which=0: h1 + n1inv(f32); which=1: h2 + n2inv(f16).
// (which==1, grp==6, b==0) also emits ksqt = f16(kp^2) in 16x16x32 A/B-frag layout.
__global__ __launch_bounds__(256) void prep_kernel(const float* __restrict__ s1,
                                                   const float* __restrict__ s2,
                                                   const float* __restrict__ kern,
                                                   float* __restrict__ n1inv,
                                                   _Float16* __restrict__ n2inv,
                                                   _Float16* __restrict__ h1,
                                                   _Float16* __restrict__ h2,
                                                   _Float16* __restrict__ ksqt) {
    const int grp   = blockIdx.x;   // 0..6 (32-row groups)
    const int which = blockIdx.y;
    const int b     = blockIdx.z;
    const float* s  = which ? s2 : s1;
    _Float16* hout  = which ? h2 : h1;
    const int r0    = grp * 32;
    const int t     = threadIdx.x;

    __shared__ float sr[32][SRS];    // 38.5 KB
    __shared__ float kq2[16][SRS];   // 19.25 KB  (total 57.75 KB -> 2 blocks/CU)

    // stage k^2 (squared once here)
    for (int idx = t; idx < 16 * 75; idx += 256) {
        int p = idx / 75, c4 = (idx - p * 75) * 4;
        float4 kv = *(const float4*)&kern[p * DD + c4];
        kv.x *= kv.x; kv.y *= kv.y; kv.z *= kv.z; kv.w *= kv.w;
        *(float4*)&kq2[p][c4] = kv;
    }
    // stage s rows (coalesced float4)
    for (int idx = t; idx < 32 * 75; idx += 256) {
        int r = idx / 75, c4 = (idx - r * 75) * 4;
        int row = r0 + r;
        float4 v = make_float4(0.f, 0.f, 0.f, 0.f);
        if (row < LL) v = *(const float4*)&s[((size_t)b * LL + row) * DD + c4];
        *(float4*)&sr[r][c4] = v;
    }
    // zero tails [300..307] so 8-wide f16 emit / frag gen can read freely
    {
        int r = t >> 3, cc = 300 + (t & 7);
        sr[r][cc] = 0.f;
        if (r < 16) kq2[r][cc] = 0.f;
    }
    __syncthreads();

    // norms: thread (r = t>>3, pq = t&7) computes p = pq and pq+8; conflict-free banks.
    {
        const int r = t >> 3, pq = t & 7;
        float acc0 = 0.f, acc1 = 0.f;
        for (int c4 = 0; c4 < 75; c4++) {
            float4 a  = *(const float4*)&sr[r][c4 * 4];
            float4 k0 = *(const float4*)&kq2[pq][c4 * 4];
            float4 k1 = *(const float4*)&kq2[pq + 8][c4 * 4];
            float x0 = a.x * a.x, x1 = a.y * a.y, x2 = a.z * a.z, x3 = a.w * a.w;
            acc0 += x0 * k0.x + x1 * k0.y + x2 * k0.z + x3 * k0.w;
            acc1 += x0 * k1.x + x1 * k1.y + x2 * k1.z + x3 * k1.w;
        }
        int row = r0 + r;
        if (row < LL) {
            float i0 = 1.0f / sqrtf(fmaxf(acc0, EPSV));
            float i1 = 1.0f / sqrtf(fmaxf(acc1, EPSV));
            if (which) {
                n2inv[((size_t)b * LL + row) * PP + pq]     = (_Float16)i0;
                n2inv[((size_t)b * LL + row) * PP + pq + 8] = (_Float16)i1;
            } else {
                n1inv[((size_t)b * LL + row) * PP + pq]     = i0;
                n1inv[((size_t)b * LL + row) * PP + pq + 8] = i1;
            }
        }
    }

    // emit f16 rows (row-major, K-padded to 320)
    for (int idx = t; idx < 32 * 40; idx += 256) {
        int r = idx / 40, e0 = (idx - r * 40) * 8;
        int row = r0 + r;
        if (row >= LL) continue;
        f16x8 h;
        if (e0 < 304) {
            float4 a = *(const float4*)&sr[r][e0];
            float4 d = *(const float4*)&sr[r][e0 + 4];
            h[0] = (_Float16)a.x; h[1] = (_Float16)a.y; h[2] = (_Float16)a.z; h[3] = (_Float16)a.w;
            h[4] = (_Float16)d.x; h[5] = (_Float16)d.y; h[6] = (_Float16)d.z; h[7] = (_Float16)d.w;
        } else {
#pragma unroll
            for (int e = 0; e < 8; e++) h[e] = (_Float16)0.f;
        }
        *(f16x8*)&hout[((size_t)b * LL + row) * KG + e0] = h;
    }

    // ksq frag table: ksqt[((ch*4+quad)*16+p)*8 + e] = f16(kp[p][ch*32+quad*8+e]^2)
    if (which == 1 && grp == 6 && b == 0) {
        for (int ent = t; ent < 640; ent += 256) {
            int ch = ent / 64, rem = ent - ch * 64;
            int quad = rem >> 4, p = rem & 15;
            int k0 = ch * 32 + quad * 8;
            f16x8 h;
            if (k0 < 304) {
                float4 a = *(const float4*)&kq2[p][k0];
                float4 d = *(const float4*)&kq2[p][k0 + 4];
                h[0] = (_Float16)a.x; h[1] = (_Float16)a.y; h[2] = (_Float16)a.z; h[3] = (_Float16)a.w;
                h[4] = (_Float16)d.x; h[5] = (_Float16)d.y; h[6] = (_Float16)d.z; h[7] = (_Float16)d.w;
            } else {
#pragma unroll
                for (int e = 0; e < 8; e++) h[e] = (_Float16)0.f;
            }
            *(f16x8*)&ksqt[(size_t)ent * 8] = h;
        }
    }
}

// ---------------- maxsim: B-tile in LDS, A-frags in registers, ksq folded into A --------
// grid 256 = (b & 63) x (jblk) x (pgrp). block 512 = 8 waves (2 waves/SIMD).
// waves 0-3: i rows [0,128); waves 4-7: i rows [72,200) (32 rows each; overlap writes are
// bit-identical, benign). B tile: 112 real j-rows + 16 DUPLICATED rows -> uniform 8 j-tiles
// (max over duplicates is a no-op). Each block does 8 of the 16 perspectives (pgrp).
__global__ __launch_bounds__(512, 2) void maxsim_kernel(const _Float16* __restrict__ h1,
                                                        const _Float16* __restrict__ h2,
                                                        const _Float16* __restrict__ ksqt,
                                                        const _Float16* __restrict__ n2inv,
                                                        float* __restrict__ part) {
    extern __shared__ __align__(16) char smem[];
    _Float16* h2s = (_Float16*)smem;          // 128*PS halfs = 84.0 KB
    _Float16* n2s = h2s + 128 * PS;           // 128*16 halfs = 4 KB

    const int blk  = blockIdx.x;
    const int b    = blk & 63;                // same-b blocks land on one XCD (stride 64 % 8 == 0)
    const int jp   = blk >> 6;                // 0..3
    const int jblk = jp >> 1;
    const int pgrp = jp & 1;
    const int j0   = jblk ? 88 : 0;
    const int t    = threadIdx.x;

    const int lane = t & 63;
    const int w    = t >> 6;                  // 8 waves
    const int c    = lane & 15;
    const int quad = lane >> 4;
    const int ibase = ((w >> 2) ? 72 : 0) + (w & 3) * 32;

    // A fragments: global -> registers (20 x b128; h1 is L2/L3-hot; latency overlaps staging)
    f16x8 af[2][NCH];
    {
        const _Float16* g1 = h1 + (size_t)b * LL * KG;
#pragma unroll
        for (int it = 0; it < 2; it++)
#pragma unroll
            for (int ch = 0; ch < NCH; ch++)
                af[it][ch] = *(const f16x8*)&g1[(size_t)(ibase + it * 16 + c) * KG + ch * 32 + quad * 8];
    }

    // stage B tile: rows 112..127 duplicate rows 96..111 (valid j, max-idempotent)
    {
        const _Float16* g2 = h2 + ((size_t)b * LL + j0) * KG;
        for (int idx = t; idx < 128 * 40; idx += 512) {
            int r = idx / 40, q = idx - r * 40;
            int sr_ = r < 112 ? r : r - 16;
            *(f16x8*)&h2s[r * PS + q * 8] = *(const f16x8*)&g2[(size_t)(sr_ * 40 + q) * 8];
        }
        const _Float16* gn = n2inv + ((size_t)b * LL + j0) * PP;
        for (int idx = t; idx < 256; idx += 512) {
            int u = (idx >> 1) < 112 ? idx : idx - 32;   // unit = 8 halfs, 2 units/row
            *(f16x8*)&n2s[idx * 8] = *(const f16x8*)&gn[(size_t)u * 8];
        }
    }
    __syncthreads();

    for (int pp = 0; pp < 4; pp++) {
        const int p0 = pgrp * 8 + pp * 2;
        float rmax[2][2][4];                   // [pq][it][r] persists across the 2 jt-passes
#pragma unroll
        for (int pq = 0; pq < 2; pq++)
#pragma unroll
            for (int it = 0; it < 2; it++)
#pragma unroll
                for (int r = 0; r < 4; r++) rmax[pq][it][r] = -INFINITY;

#pragma unroll
        for (int pass = 0; pass < 2; pass++) {
            const int jt0 = pass * 4;
            f32x4v acc[2][2][4];               // [pq][it][jt] (64 VGPRs)
#pragma unroll
            for (int pq = 0; pq < 2; pq++)
#pragma unroll
                for (int it = 0; it < 2; it++)
#pragma unroll
                    for (int jt = 0; jt < 4; jt++) acc[pq][it][jt] = (f32x4v)0.f;

            f16x8 kq[2][2];
            kq[0][0] = *(const f16x8*)&ksqt[quad * 128 + p0 * 8];
            kq[0][1] = *(const f16x8*)&ksqt[quad * 128 + p0 * 8 + 8];
#pragma unroll
            for (int ch = 0; ch < NCH; ch++) {
                const int cur = ch & 1, nxt = cur ^ 1;
                if (ch < NCH - 1) {            // prefetch next chunk's ksq frags (L2-hot 10 KB)
                    kq[nxt][0] = *(const f16x8*)&ksqt[(ch + 1) * 512 + quad * 128 + p0 * 8];
                    kq[nxt][1] = *(const f16x8*)&ksqt[(ch + 1) * 512 + quad * 128 + p0 * 8 + 8];
                }
                // fold ksq into the A side: 16 pk_muls feed 16 MFMAs (vs 56 on the B side)
                f16x8 sa00 = af[0][ch] * kq[cur][0];
                f16x8 sa10 = af[1][ch] * kq[cur][0];
                f16x8 sa01 = af[0][ch] * kq[cur][1];
                f16x8 sa11 = af[1][ch] * kq[cur][1];
#pragma unroll
                for (int jt = 0; jt < 4; jt++) {
                    f16x8 hb = *(const f16x8*)&h2s[((jt0 + jt) * 16 + c) * PS + ch * 32 + quad * 8];
                    acc[0][0][jt] = __builtin_amdgcn_mfma_f32_16x16x32_f16(sa00, hb, acc[0][0][jt], 0, 0, 0);
                    acc[0][1][jt] = __builtin_amdgcn_mfma_f32_16x16x32_f16(sa10, hb, acc[0][1][jt], 0, 0, 0);
                    acc[1][0][jt] = __builtin_amdgcn_mfma_f32_16x16x32_f16(sa01, hb, acc[1][0][jt], 0, 0, 0);
                    acc[1][1][jt] = __builtin_amdgcn_mfma_f32_16x16x32_f16(sa11, hb, acc[1][1][jt], 0, 0, 0);
                }
            }
            // fold this pass into rmax: scale cols by n2, max over j-tiles
#pragma unroll
            for (int pq = 0; pq < 2; pq++)
#pragma unroll
                for (int jt = 0; jt < 4; jt++) {
                    float n2 = (float)n2s[((jt0 + jt) * 16 + c) * PP + p0 + pq];
#pragma unroll
                    for (int it = 0; it < 2; it++)
#pragma unroll
                        for (int r = 0; r < 4; r++)
                            rmax[pq][it][r] = fmaxf(rmax[pq][it][r], acc[pq][it][jt][r] * n2);
                }
        }

        // reduce over j-col (lane bits 0..3) and write (C/D: col=lane&15=j, row=quad*4+r)
#pragma unroll
        for (int pq = 0; pq < 2; pq++) {
#pragma unroll
            for (int m = 1; m <= 8; m <<= 1)
#pragma unroll
                for (int it = 0; it < 2; it++)
#pragma unroll
                    for (int r = 0; r < 4; r++)
                        rmax[pq][it][r] = fmaxf(rmax[pq][it][r], __shfl_xor(rmax[pq][it][r], m));
            if (c == 0) {
#pragma unroll
                for (int it = 0; it < 2; it++)
#pragma unroll
                    for (int r = 0; r < 4; r++) {
                        int i = ibase + it * 16 + quad * 4 + r;   // < 200 by construction
                        part[((size_t)jblk * BBATCH + b) * (LL * PP) + (size_t)i * PP + p0 + pq] = rmax[pq][it][r];
                    }
            }
        }
    }
}

// ---------------- reduce: out = max(part0, part1) * n1inv --------------------------------
__global__ __launch_bounds__(256) void reduce_kernel(const float* __restrict__ part,
                                                     const float* __restrict__ n1inv,
                                                     float* __restrict__ out) {
    int tid = blockIdx.x * 256 + threadIdx.x;
    if (tid >= BBATCH * LL * PP) return;
    out[tid] = fmaxf(part[tid], part[(size_t)BBATCH * LL * PP + tid]) * n1inv[tid];
}

extern "C" void kernel_launch(void* const* d_in, const int* in_sizes, int n_in,
                              void* d_out, int out_size, void* d_ws, size_t ws_size,
                              hipStream_t stream) {
    const float* sent1  = (const float*)d_in[0];   // (64,200,300) f32
    const float* sent2  = (const float*)d_in[1];   // (64,200,300) f32
    const float* kernel = (const float*)d_in[2];   // (16,300)     f32
    float* out = (float*)d_out;                    // (64,200,16)  f32

    char* ws = (char*)d_ws;
    float*    n1inv = (float*)ws;                  ws += (size_t)BBATCH * LL * PP * 4;   // 0.82 MB
    _Float16* n2inv = (_Float16*)ws;               ws += (size_t)BBATCH * LL * PP * 2;   // 0.41 MB
    _Float16* h1    = (_Float16*)ws;               ws += (size_t)BBATCH * LL * KG * 2;   // 8.19 MB
    _Float16* h2    = (_Float16*)ws;               ws += (size_t)BBATCH * LL * KG * 2;   // 8.19 MB
    _Float16* ksqt  = (_Float16*)ws;               ws += (size_t)640 * 8 * 2;            // 10 KB
    float*    part  = (float*)ws;                  // 2*64*200*16 f32 = 1.64 MB (total ~19.3 MB)

    prep_kernel<<<dim3(7, 2, BBATCH), 256, 0, stream>>>(sent1, sent2, kernel,
                                                        n1inv, n2inv, h1, h2, ksqt);

    const int lds_bytes = (128 * PS + 128 * PP) * 2;   // 88,064 B
    hipFuncSetAttribute((const void*)maxsim_kernel,
                        hipFuncAttributeMaxDynamicSharedMemorySize, lds_bytes);
    maxsim_kernel<<<dim3(256, 1, 1), 512, lds_bytes, stream>>>(h1, h2, ksqt, n2inv, part);

    int nout = BBATCH * LL * PP;
    reduce_kernel<<<(nout + 255) / 256, 256, 0, stream>>>(part, n1inv, out);
}

// Round 3
// 303.737 us; speedup vs baseline: 1.0011x; 1.0011x over previous
//
#include <hip/hip_runtime.h>
#include <math.h>

#define BBATCH 64
#define LL 200
#define DD 300
#define PP 16
#define EPSV 1e-12f
#define KG 320          // global K-pad (10 chunks of 32)
#define PS 328          // maxsim LDS row stride in halfs (656 B: 4-bank row shift)
#define NCH 10
#define SRS 308         // prep LDS row stride in f32: 308 mod 32 = 12 -> 8-row groups hit all 32 banks

typedef _Float16 f16x8 __attribute__((ext_vector_type(8)));
typedef float f32x4v __attribute__((ext_vector_type(4)));

// ---------------- prep: norms + f16 conversion + ksq frag table --------------------------
// grid (7, 2, 64), block 256. 32 rows/block. which=0: h1 + n1inv(f32); which=1: h2 + n2inv(f16).
// (which==1, grp==6, b==0) also emits ksqt = f16(kp^2) in 16x16x32 A/B-frag layout.
__global__ __launch_bounds__(256) void prep_kernel(const float* __restrict__ s1,
                                                   const float* __restrict__ s2,
                                                   const float* __restrict__ kern,
                                                   float* __restrict__ n1inv,
                                                   _Float16* __restrict__ n2inv,
                                                   _Float16* __restrict__ h1,
                                                   _Float16* __restrict__ h2,
                                                   _Float16* __restrict__ ksqt) {
    const int grp   = blockIdx.x;   // 0..6 (32-row groups)
    const int which = blockIdx.y;
    const int b     = blockIdx.z;
    const float* s  = which ? s2 : s1;
    _Float16* hout  = which ? h2 : h1;
    const int r0    = grp * 32;
    const int t     = threadIdx.x;

    __shared__ float sr[32][SRS];    // 38.5 KB
    __shared__ float kq2[16][SRS];   // 19.25 KB  (total 57.75 KB -> 2 blocks/CU)

    // stage k^2 (squared once here)
    for (int idx = t; idx < 16 * 75; idx += 256) {
        int p = idx / 75, c4 = (idx - p * 75) * 4;
        float4 kv = *(const float4*)&kern[p * DD + c4];
        kv.x *= kv.x; kv.y *= kv.y; kv.z *= kv.z; kv.w *= kv.w;
        *(float4*)&kq2[p][c4] = kv;
    }
    // stage s rows (coalesced float4)
    for (int idx = t; idx < 32 * 75; idx += 256) {
        int r = idx / 75, c4 = (idx - r * 75) * 4;
        int row = r0 + r;
        float4 v = make_float4(0.f, 0.f, 0.f, 0.f);
        if (row < LL) v = *(const float4*)&s[((size_t)b * LL + row) * DD + c4];
        *(float4*)&sr[r][c4] = v;
    }
    // zero tails [300..307] so 8-wide f16 emit / frag gen can read freely
    {
        int r = t >> 3, cc = 300 + (t & 7);
        sr[r][cc] = 0.f;
        if (r < 16) kq2[r][cc] = 0.f;
    }
    __syncthreads();

    // norms: thread (r = t>>3, pq = t&7) computes p = pq and pq+8; conflict-free banks.
    {
        const int r = t >> 3, pq = t & 7;
        float acc0 = 0.f, acc1 = 0.f;
        for (int c4 = 0; c4 < 75; c4++) {
            float4 a  = *(const float4*)&sr[r][c4 * 4];
            float4 k0 = *(const float4*)&kq2[pq][c4 * 4];
            float4 k1 = *(const float4*)&kq2[pq + 8][c4 * 4];
            float x0 = a.x * a.x, x1 = a.y * a.y, x2 = a.z * a.z, x3 = a.w * a.w;
            acc0 += x0 * k0.x + x1 * k0.y + x2 * k0.z + x3 * k0.w;
            acc1 += x0 * k1.x + x1 * k1.y + x2 * k1.z + x3 * k1.w;
        }
        int row = r0 + r;
        if (row < LL) {
            float i0 = 1.0f / sqrtf(fmaxf(acc0, EPSV));
            float i1 = 1.0f / sqrtf(fmaxf(acc1, EPSV));
            if (which) {
                n2inv[((size_t)b * LL + row) * PP + pq]     = (_Float16)i0;
                n2inv[((size_t)b * LL + row) * PP + pq + 8] = (_Float16)i1;
            } else {
                n1inv[((size_t)b * LL + row) * PP + pq]     = i0;
                n1inv[((size_t)b * LL + row) * PP + pq + 8] = i1;
            }
        }
    }

    // emit f16 rows (row-major, K-padded to 320)
    for (int idx = t; idx < 32 * 40; idx += 256) {
        int r = idx / 40, e0 = (idx - r * 40) * 8;
        int row = r0 + r;
        if (row >= LL) continue;
        f16x8 h;
        if (e0 < 304) {
            float4 a = *(const float4*)&sr[r][e0];
            float4 d = *(const float4*)&sr[r][e0 + 4];
            h[0] = (_Float16)a.x; h[1] = (_Float16)a.y; h[2] = (_Float16)a.z; h[3] = (_Float16)a.w;
            h[4] = (_Float16)d.x; h[5] = (_Float16)d.y; h[6] = (_Float16)d.z; h[7] = (_Float16)d.w;
        } else {
#pragma unroll
            for (int e = 0; e < 8; e++) h[e] = (_Float16)0.f;
        }
        *(f16x8*)&hout[((size_t)b * LL + row) * KG + e0] = h;
    }

    // ksq frag table: ksqt[((ch*4+quad)*16+p)*8 + e] = f16(kp[p][ch*32+quad*8+e]^2)
    if (which == 1 && grp == 6 && b == 0) {
        for (int ent = t; ent < 640; ent += 256) {
            int ch = ent / 64, rem = ent - ch * 64;
            int quad = rem >> 4, p = rem & 15;
            int k0 = ch * 32 + quad * 8;
            f16x8 h;
            if (k0 < 304) {
                float4 a = *(const float4*)&kq2[p][k0];
                float4 d = *(const float4*)&kq2[p][k0 + 4];
                h[0] = (_Float16)a.x; h[1] = (_Float16)a.y; h[2] = (_Float16)a.z; h[3] = (_Float16)a.w;
                h[4] = (_Float16)d.x; h[5] = (_Float16)d.y; h[6] = (_Float16)d.z; h[7] = (_Float16)d.w;
            } else {
#pragma unroll
                for (int e = 0; e < 8; e++) h[e] = (_Float16)0.f;
            }
            *(f16x8*)&ksqt[(size_t)ent * 8] = h;
        }
    }
}

// ---------------- maxsim: B-tile in LDS, A-frags in registers, ksq folded into A --------
// grid 256 = (b & 63) x (jblk) x (pgrp). block 512 = 8 waves.
// __launch_bounds__(512, 1): 1 block/CU min. The 8-wave block forces 2 waves/SIMD
// co-resident -> per-wave VGPR cap 256 (NOT 128: round-1's (512,2) was read as
// 2 blocks/CU -> 128-cap -> ~570 MB/dispatch scratch spill traffic).
// waves 0-3: i rows [0,128); waves 4-7: i rows [72,200) (32 rows each; overlap writes are
// bit-identical, benign). B tile: 112 real j-rows + 16 DUPLICATED rows -> uniform 8 j-tiles
// (max over duplicates is a no-op). Each block does 8 of the 16 perspectives (pgrp).
__global__ __launch_bounds__(512, 1) void maxsim_kernel(const _Float16* __restrict__ h1,
                                                        const _Float16* __restrict__ h2,
                                                        const _Float16* __restrict__ ksqt,
                                                        const _Float16* __restrict__ n2inv,
                                                        float* __restrict__ part) {
    extern __shared__ __align__(16) char smem[];
    _Float16* h2s = (_Float16*)smem;          // 128*PS halfs = 84.0 KB
    _Float16* n2s = h2s + 128 * PS;           // 128*16 halfs = 4 KB

    const int blk  = blockIdx.x;
    const int b    = blk & 63;                // same-b blocks land on one XCD (stride 64 % 8 == 0)
    const int jp   = blk >> 6;                // 0..3
    const int jblk = jp >> 1;
    const int pgrp = jp & 1;
    const int j0   = jblk ? 88 : 0;
    const int t    = threadIdx.x;

    const int lane = t & 63;
    const int w    = t >> 6;                  // 8 waves
    const int c    = lane & 15;
    const int quad = lane >> 4;
    const int ibase = ((w >> 2) ? 72 : 0) + (w & 3) * 32;

    // A fragments: global -> registers (20 x b128; h1 is L2/L3-hot; latency overlaps staging)
    f16x8 af[2][NCH];
    {
        const _Float16* g1 = h1 + (size_t)b * LL * KG;
#pragma unroll
        for (int it = 0; it < 2; it++)
#pragma unroll
            for (int ch = 0; ch < NCH; ch++)
                af[it][ch] = *(const f16x8*)&g1[(size_t)(ibase + it * 16 + c) * KG + ch * 32 + quad * 8];
    }

    // stage B tile: rows 112..127 duplicate rows 96..111 (valid j, max-idempotent)
    {
        const _Float16* g2 = h2 + ((size_t)b * LL + j0) * KG;
        for (int idx = t; idx < 128 * 40; idx += 512) {
            int r = idx / 40, q = idx - r * 40;
            int sr_ = r < 112 ? r : r - 16;
            *(f16x8*)&h2s[r * PS + q * 8] = *(const f16x8*)&g2[(size_t)(sr_ * 40 + q) * 8];
        }
        const _Float16* gn = n2inv + ((size_t)b * LL + j0) * PP;
        for (int idx = t; idx < 256; idx += 512) {
            int u = (idx >> 1) < 112 ? idx : idx - 32;   // unit = 8 halfs, 2 units/row
            *(f16x8*)&n2s[idx * 8] = *(const f16x8*)&gn[(size_t)u * 8];
        }
    }
    __syncthreads();

    for (int pp = 0; pp < 4; pp++) {
        const int p0 = pgrp * 8 + pp * 2;
        float rmax[2][2][4];                   // [pq][it][r] persists across the 2 jt-passes
#pragma unroll
        for (int pq = 0; pq < 2; pq++)
#pragma unroll
            for (int it = 0; it < 2; it++)
#pragma unroll
                for (int r = 0; r < 4; r++) rmax[pq][it][r] = -INFINITY;

#pragma unroll
        for (int pass = 0; pass < 2; pass++) {
            const int jt0 = pass * 4;
            f32x4v acc[2][2][4];               // [pq][it][jt] (64 VGPRs)
#pragma unroll
            for (int pq = 0; pq < 2; pq++)
#pragma unroll
                for (int it = 0; it < 2; it++)
#pragma unroll
                    for (int jt = 0; jt < 4; jt++) acc[pq][it][jt] = (f32x4v)0.f;

            f16x8 kq[2][2];
            kq[0][0] = *(const f16x8*)&ksqt[quad * 128 + p0 * 8];
            kq[0][1] = *(const f16x8*)&ksqt[quad * 128 + p0 * 8 + 8];
#pragma unroll
            for (int ch = 0; ch < NCH; ch++) {
                const int cur = ch & 1, nxt = cur ^ 1;
                if (ch < NCH - 1) {            // prefetch next chunk's ksq frags (L2-hot 10 KB)
                    kq[nxt][0] = *(const f16x8*)&ksqt[(ch + 1) * 512 + quad * 128 + p0 * 8];
                    kq[nxt][1] = *(const f16x8*)&ksqt[(ch + 1) * 512 + quad * 128 + p0 * 8 + 8];
                }
                // fold ksq into the A side: 16 pk_muls feed 16 MFMAs (vs 56 on the B side)
                f16x8 sa00 = af[0][ch] * kq[cur][0];
                f16x8 sa10 = af[1][ch] * kq[cur][0];
                f16x8 sa01 = af[0][ch] * kq[cur][1];
                f16x8 sa11 = af[1][ch] * kq[cur][1];
#pragma unroll
                for (int jt = 0; jt < 4; jt++) {
                    f16x8 hb = *(const f16x8*)&h2s[((jt0 + jt) * 16 + c) * PS + ch * 32 + quad * 8];
                    acc[0][0][jt] = __builtin_amdgcn_mfma_f32_16x16x32_f16(sa00, hb, acc[0][0][jt], 0, 0, 0);
                    acc[0][1][jt] = __builtin_amdgcn_mfma_f32_16x16x32_f16(sa10, hb, acc[0][1][jt], 0, 0, 0);
                    acc[1][0][jt] = __builtin_amdgcn_mfma_f32_16x16x32_f16(sa01, hb, acc[1][0][jt], 0, 0, 0);
                    acc[1][1][jt] = __builtin_amdgcn_mfma_f32_16x16x32_f16(sa11, hb, acc[1][1][jt], 0, 0, 0);
                }
            }
            // fold this pass into rmax: scale cols by n2, max over j-tiles
#pragma unroll
            for (int pq = 0; pq < 2; pq++)
#pragma unroll
                for (int jt = 0; jt < 4; jt++) {
                    float n2 = (float)n2s[((jt0 + jt) * 16 + c) * PP + p0 + pq];
#pragma unroll
                    for (int it = 0; it < 2; it++)
#pragma unroll
                        for (int r = 0; r < 4; r++)
                            rmax[pq][it][r] = fmaxf(rmax[pq][it][r], acc[pq][it][jt][r] * n2);
                }
        }

        // reduce over j-col (lane bits 0..3) and write (C/D: col=lane&15=j, row=quad*4+r)
#pragma unroll
        for (int pq = 0; pq < 2; pq++) {
#pragma unroll
            for (int m = 1; m <= 8; m <<= 1)
#pragma unroll
                for (int it = 0; it < 2; it++)
#pragma unroll
                    for (int r = 0; r < 4; r++)
                        rmax[pq][it][r] = fmaxf(rmax[pq][it][r], __shfl_xor(rmax[pq][it][r], m));
            if (c == 0) {
#pragma unroll
                for (int it = 0; it < 2; it++)
#pragma unroll
                    for (int r = 0; r < 4; r++) {
                        int i = ibase + it * 16 + quad * 4 + r;   // < 200 by construction
                        part[((size_t)jblk * BBATCH + b) * (LL * PP) + (size_t)i * PP + p0 + pq] = rmax[pq][it][r];
                    }
            }
        }
    }
}

// ---------------- reduce: out = max(part0, part1) * n1inv --------------------------------
__global__ __launch_bounds__(256) void reduce_kernel(const float* __restrict__ part,
                                                     const float* __restrict__ n1inv,
                                                     float* __restrict__ out) {
    int tid = blockIdx.x * 256 + threadIdx.x;
    if (tid >= BBATCH * LL * PP) return;
    out[tid] = fmaxf(part[tid], part[(size_t)BBATCH * LL * PP + tid]) * n1inv[tid];
}

extern "C" void kernel_launch(void* const* d_in, const int* in_sizes, int n_in,
                              void* d_out, int out_size, void* d_ws, size_t ws_size,
                              hipStream_t stream) {
    const float* sent1  = (const float*)d_in[0];   // (64,200,300) f32
    const float* sent2  = (const float*)d_in[1];   // (64,200,300) f32
    const float* kernel = (const float*)d_in[2];   // (16,300)     f32
    float* out = (float*)d_out;                    // (64,200,16)  f32

    char* ws = (char*)d_ws;
    float*    n1inv = (float*)ws;                  ws += (size_t)BBATCH * LL * PP * 4;   // 0.82 MB
    _Float16* n2inv = (_Float16*)ws;               ws += (size_t)BBATCH * LL * PP * 2;   // 0.41 MB
    _Float16* h1    = (_Float16*)ws;               ws += (size_t)BBATCH * LL * KG * 2;   // 8.19 MB
    _Float16* h2    = (_Float16*)ws;               ws += (size_t)BBATCH * LL * KG * 2;   // 8.19 MB
    _Float16* ksqt  = (_Float16*)ws;               ws += (size_t)640 * 8 * 2;            // 10 KB
    float*    part  = (float*)ws;                  // 2*64*200*16 f32 = 1.64 MB (total ~19.3 MB)

    prep_kernel<<<dim3(7, 2, BBATCH), 256, 0, stream>>>(sent1, sent2, kernel,
                                                        n1inv, n2inv, h1, h2, ksqt);

    const int lds_bytes = (128 * PS + 128 * PP) * 2;   // 88,064 B
    hipFuncSetAttribute((const void*)maxsim_kernel,
                        hipFuncAttributeMaxDynamicSharedMemorySize, lds_bytes);
    maxsim_kernel<<<dim3(256, 1, 1), 512, lds_bytes, stream>>>(h1, h2, ksqt, n2inv, part);

    int nout = BBATCH * LL * PP;
    reduce_kernel<<<(nout + 255) / 256, 256, 0, stream>>>(part, n1inv, out);
}

// Round 4
// 235.259 us; speedup vs baseline: 1.2926x; 1.2911x over previous
//
#include <hip/hip_runtime.h>
#include <math.h>

#define BBATCH 64
#define LL 200
#define DD 300
#define PP 16
#define EPSV 1e-12f
#define KG 320          // global K-pad (10 chunks of 32)
#define PS 328          // maxsim LDS row stride in halfs (656 B: 4-bank row shift)
#define NCH 10
#define SRS 308         // prep LDS row stride in f32: 308 mod 32 = 12 -> 8-row groups hit all 32 banks

typedef _Float16 f16x8 __attribute__((ext_vector_type(8)));
typedef float f32x4v __attribute__((ext_vector_type(4)));

// ---------------- prep: norms + f16 conversion + ksq frag table --------------------------
// grid (7, 2, 64), block 256. 32 rows/block. which=0: h1 + n1inv(f32); which=1: h2 + n2inv(f16).
// (which==1, grp==6, b==0) also emits ksqt = f16(kp^2) in 16x16x32 A/B-frag layout.
__global__ __launch_bounds__(256) void prep_kernel(const float* __restrict__ s1,
                                                   const float* __restrict__ s2,
                                                   const float* __restrict__ kern,
                                                   float* __restrict__ n1inv,
                                                   _Float16* __restrict__ n2inv,
                                                   _Float16* __restrict__ h1,
                                                   _Float16* __restrict__ h2,
                                                   _Float16* __restrict__ ksqt) {
    const int grp   = blockIdx.x;   // 0..6 (32-row groups)
    const int which = blockIdx.y;
    const int b     = blockIdx.z;
    const float* s  = which ? s2 : s1;
    _Float16* hout  = which ? h2 : h1;
    const int r0    = grp * 32;
    const int t     = threadIdx.x;

    __shared__ float sr[32][SRS];    // 38.5 KB
    __shared__ float kq2[16][SRS];   // 19.25 KB  (total 57.75 KB -> 2 blocks/CU)

    // stage k^2 (squared once here)
    for (int idx = t; idx < 16 * 75; idx += 256) {
        int p = idx / 75, c4 = (idx - p * 75) * 4;
        float4 kv = *(const float4*)&kern[p * DD + c4];
        kv.x *= kv.x; kv.y *= kv.y; kv.z *= kv.z; kv.w *= kv.w;
        *(float4*)&kq2[p][c4] = kv;
    }
    // stage s rows (coalesced float4)
    for (int idx = t; idx < 32 * 75; idx += 256) {
        int r = idx / 75, c4 = (idx - r * 75) * 4;
        int row = r0 + r;
        float4 v = make_float4(0.f, 0.f, 0.f, 0.f);
        if (row < LL) v = *(const float4*)&s[((size_t)b * LL + row) * DD + c4];
        *(float4*)&sr[r][c4] = v;
    }
    // zero tails [300..307] so 8-wide f16 emit / frag gen can read freely
    {
        int r = t >> 3, cc = 300 + (t & 7);
        sr[r][cc] = 0.f;
        if (r < 16) kq2[r][cc] = 0.f;
    }
    __syncthreads();

    // norms: thread (r = t>>3, pq = t&7) computes p = pq and pq+8; conflict-free banks.
    {
        const int r = t >> 3, pq = t & 7;
        float acc0 = 0.f, acc1 = 0.f;
        for (int c4 = 0; c4 < 75; c4++) {
            float4 a  = *(const float4*)&sr[r][c4 * 4];
            float4 k0 = *(const float4*)&kq2[pq][c4 * 4];
            float4 k1 = *(const float4*)&kq2[pq + 8][c4 * 4];
            float x0 = a.x * a.x, x1 = a.y * a.y, x2 = a.z * a.z, x3 = a.w * a.w;
            acc0 += x0 * k0.x + x1 * k0.y + x2 * k0.z + x3 * k0.w;
            acc1 += x0 * k1.x + x1 * k1.y + x2 * k1.z + x3 * k1.w;
        }
        int row = r0 + r;
        if (row < LL) {
            float i0 = 1.0f / sqrtf(fmaxf(acc0, EPSV));
            float i1 = 1.0f / sqrtf(fmaxf(acc1, EPSV));
            if (which) {
                n2inv[((size_t)b * LL + row) * PP + pq]     = (_Float16)i0;
                n2inv[((size_t)b * LL + row) * PP + pq + 8] = (_Float16)i1;
            } else {
                n1inv[((size_t)b * LL + row) * PP + pq]     = i0;
                n1inv[((size_t)b * LL + row) * PP + pq + 8] = i1;
            }
        }
    }

    // emit f16 rows (row-major, K-padded to 320)
    for (int idx = t; idx < 32 * 40; idx += 256) {
        int r = idx / 40, e0 = (idx - r * 40) * 8;
        int row = r0 + r;
        if (row >= LL) continue;
        f16x8 h;
        if (e0 < 304) {
            float4 a = *(const float4*)&sr[r][e0];
            float4 d = *(const float4*)&sr[r][e0 + 4];
            h[0] = (_Float16)a.x; h[1] = (_Float16)a.y; h[2] = (_Float16)a.z; h[3] = (_Float16)a.w;
            h[4] = (_Float16)d.x; h[5] = (_Float16)d.y; h[6] = (_Float16)d.z; h[7] = (_Float16)d.w;
        } else {
#pragma unroll
            for (int e = 0; e < 8; e++) h[e] = (_Float16)0.f;
        }
        *(f16x8*)&hout[((size_t)b * LL + row) * KG + e0] = h;
    }

    // ksq frag table: ksqt[((ch*4+quad)*16+p)*8 + e] = f16(kp[p][ch*32+quad*8+e]^2)
    if (which == 1 && grp == 6 && b == 0) {
        for (int ent = t; ent < 640; ent += 256) {
            int ch = ent / 64, rem = ent - ch * 64;
            int quad = rem >> 4, p = rem & 15;
            int k0 = ch * 32 + quad * 8;
            f16x8 h;
            if (k0 < 304) {
                float4 a = *(const float4*)&kq2[p][k0];
                float4 d = *(const float4*)&kq2[p][k0 + 4];
                h[0] = (_Float16)a.x; h[1] = (_Float16)a.y; h[2] = (_Float16)a.z; h[3] = (_Float16)a.w;
                h[4] = (_Float16)d.x; h[5] = (_Float16)d.y; h[6] = (_Float16)d.z; h[7] = (_Float16)d.w;
            } else {
#pragma unroll
                for (int e = 0; e < 8; e++) h[e] = (_Float16)0.f;
            }
            *(f16x8*)&ksqt[(size_t)ent * 8] = h;
        }
    }
}

// ---------------- maxsim: 256-thr / 4-wave blocks, B-tile in LDS, A-frags in registers --
// EMPIRICAL (r1/r3): 512-thread blocks get a hard 128-VGPR cap on this toolchain no matter
// the launch_bounds 2nd arg -> ~580 MB scratch spill. 256-thread blocks reach 256 VGPRs
// (r0 measured). So: 4-wave blocks, 2 blocks/CU via 77 KB LDS -> 2 waves/SIMD.
// grid 512 = (b) x (iblk) x (pgrp) x (jblk). Each wave: 32 i-rows in regs (af, 80 VGPR).
// iblk0 rows 0-127, iblk1 rows 72-199 (overlap writes bit-identical, benign).
// B tile: 112 real j-rows (7 j-tiles, r0-proven layout), jt split 4+3 keeps acc at 64 VGPR.
// ksq folded into A side: 4 pk_muls feed 16 MFMAs per (ch, pass).
__global__ __launch_bounds__(256, 2) void maxsim_kernel(const _Float16* __restrict__ h1,
                                                        const _Float16* __restrict__ h2,
                                                        const _Float16* __restrict__ ksqt,
                                                        const _Float16* __restrict__ n2inv,
                                                        float* __restrict__ part) {
    extern __shared__ __align__(16) char smem[];
    _Float16* h2s = (_Float16*)smem;          // 112*PS halfs = 73,472 B
    _Float16* n2s = h2s + 112 * PS;           // 112*16 halfs =  3,584 B  (total 77,056)

    const int blk  = blockIdx.x;
    const int b    = blk & 63;
    const int v    = blk >> 6;                // 0..7
    const int iblk = v & 1;
    const int pgrp = (v >> 1) & 1;
    const int jblk = v >> 2;
    const int i0   = iblk ? 72 : 0;
    const int j0   = jblk ? 88 : 0;
    const int t    = threadIdx.x;

    const int lane = t & 63;
    const int w    = t >> 6;                  // 4 waves
    const int c    = lane & 15;
    const int quad = lane >> 4;
    const int ibase = i0 + w * 32;

    // A fragments: global -> registers (20 x b128; h1 is L2/L3-hot; latency overlaps staging)
    f16x8 af[2][NCH];
    {
        const _Float16* g1 = h1 + (size_t)b * LL * KG;
#pragma unroll
        for (int it = 0; it < 2; it++)
#pragma unroll
            for (int ch = 0; ch < NCH; ch++)
                af[it][ch] = *(const f16x8*)&g1[(size_t)(ibase + it * 16 + c) * KG + ch * 32 + quad * 8];
    }

    // stage B tile (112 rows, row-contiguous global -> padded-stride LDS) + n2
    {
        const _Float16* g2 = h2 + ((size_t)b * LL + j0) * KG;
        for (int idx = t; idx < 112 * 40; idx += 256) {
            int r = idx / 40, q = idx - r * 40;
            *(f16x8*)&h2s[r * PS + q * 8] = *(const f16x8*)&g2[(size_t)idx * 8];
        }
        const _Float16* gn = n2inv + ((size_t)b * LL + j0) * PP;
        for (int idx = t; idx < 224; idx += 256)
            *(f16x8*)&n2s[idx * 8] = *(const f16x8*)&gn[(size_t)idx * 8];
    }
    __syncthreads();

    for (int pp = 0; pp < 4; pp++) {
        const int p0 = pgrp * 8 + pp * 2;
        float rmax[2][2][4];                   // [pq][it][r] persists across the 2 jt-passes
#pragma unroll
        for (int pq = 0; pq < 2; pq++)
#pragma unroll
            for (int it = 0; it < 2; it++)
#pragma unroll
                for (int r = 0; r < 4; r++) rmax[pq][it][r] = -INFINITY;

#pragma unroll
        for (int pass = 0; pass < 2; pass++) {
            const int jt0 = pass * 4;
            const int jn  = pass ? 3 : 4;      // 7 j-tiles total, split 4+3
            f32x4v acc[2][2][4];               // [pq][it][jt] (64 VGPRs)
#pragma unroll
            for (int pq = 0; pq < 2; pq++)
#pragma unroll
                for (int it = 0; it < 2; it++)
#pragma unroll
                    for (int jt = 0; jt < 4; jt++) acc[pq][it][jt] = (f32x4v)0.f;

            f16x8 kq[2][2];
            kq[0][0] = *(const f16x8*)&ksqt[quad * 128 + p0 * 8];
            kq[0][1] = *(const f16x8*)&ksqt[quad * 128 + p0 * 8 + 8];
#pragma unroll
            for (int ch = 0; ch < NCH; ch++) {
                const int cur = ch & 1, nxt = cur ^ 1;
                if (ch < NCH - 1) {            // prefetch next chunk's ksq frags (L2-hot 10 KB)
                    kq[nxt][0] = *(const f16x8*)&ksqt[(ch + 1) * 512 + quad * 128 + p0 * 8];
                    kq[nxt][1] = *(const f16x8*)&ksqt[(ch + 1) * 512 + quad * 128 + p0 * 8 + 8];
                }
                // fold ksq into the A side: 4 pk_muls feed up to 16 MFMAs
                f16x8 sa00 = af[0][ch] * kq[cur][0];
                f16x8 sa10 = af[1][ch] * kq[cur][0];
                f16x8 sa01 = af[0][ch] * kq[cur][1];
                f16x8 sa11 = af[1][ch] * kq[cur][1];
#pragma unroll
                for (int jt = 0; jt < 4; jt++) {
                    if (jt < jn) {
                        f16x8 hb = *(const f16x8*)&h2s[((jt0 + jt) * 16 + c) * PS + ch * 32 + quad * 8];
                        acc[0][0][jt] = __builtin_amdgcn_mfma_f32_16x16x32_f16(sa00, hb, acc[0][0][jt], 0, 0, 0);
                        acc[0][1][jt] = __builtin_amdgcn_mfma_f32_16x16x32_f16(sa10, hb, acc[0][1][jt], 0, 0, 0);
                        acc[1][0][jt] = __builtin_amdgcn_mfma_f32_16x16x32_f16(sa01, hb, acc[1][0][jt], 0, 0, 0);
                        acc[1][1][jt] = __builtin_amdgcn_mfma_f32_16x16x32_f16(sa11, hb, acc[1][1][jt], 0, 0, 0);
                    }
                }
            }
            // fold this pass into rmax: scale cols by n2, max over j-tiles
#pragma unroll
            for (int pq = 0; pq < 2; pq++)
#pragma unroll
                for (int jt = 0; jt < 4; jt++) {
                    if (jt < jn) {
                        float n2 = (float)n2s[((jt0 + jt) * 16 + c) * PP + p0 + pq];
#pragma unroll
                        for (int it = 0; it < 2; it++)
#pragma unroll
                            for (int r = 0; r < 4; r++)
                                rmax[pq][it][r] = fmaxf(rmax[pq][it][r], acc[pq][it][jt][r] * n2);
                    }
                }
        }

        // reduce over j-col (lane bits 0..3) and write (C/D: col=lane&15=j, row=quad*4+r)
#pragma unroll
        for (int pq = 0; pq < 2; pq++) {
#pragma unroll
            for (int m = 1; m <= 8; m <<= 1)
#pragma unroll
                for (int it = 0; it < 2; it++)
#pragma unroll
                    for (int r = 0; r < 4; r++)
                        rmax[pq][it][r] = fmaxf(rmax[pq][it][r], __shfl_xor(rmax[pq][it][r], m));
            if (c == 0) {
#pragma unroll
                for (int it = 0; it < 2; it++)
#pragma unroll
                    for (int r = 0; r < 4; r++) {
                        int i = ibase + it * 16 + quad * 4 + r;   // < 200 by construction
                        part[((size_t)jblk * BBATCH + b) * (LL * PP) + (size_t)i * PP + p0 + pq] = rmax[pq][it][r];
                    }
            }
        }
    }
}

// ---------------- reduce: out = max(part0, part1) * n1inv --------------------------------
__global__ __launch_bounds__(256) void reduce_kernel(const float* __restrict__ part,
                                                     const float* __restrict__ n1inv,
                                                     float* __restrict__ out) {
    int tid = blockIdx.x * 256 + threadIdx.x;
    if (tid >= BBATCH * LL * PP) return;
    out[tid] = fmaxf(part[tid], part[(size_t)BBATCH * LL * PP + tid]) * n1inv[tid];
}

extern "C" void kernel_launch(void* const* d_in, const int* in_sizes, int n_in,
                              void* d_out, int out_size, void* d_ws, size_t ws_size,
                              hipStream_t stream) {
    const float* sent1  = (const float*)d_in[0];   // (64,200,300) f32
    const float* sent2  = (const float*)d_in[1];   // (64,200,300) f32
    const float* kernel = (const float*)d_in[2];   // (16,300)     f32
    float* out = (float*)d_out;                    // (64,200,16)  f32

    char* ws = (char*)d_ws;
    float*    n1inv = (float*)ws;                  ws += (size_t)BBATCH * LL * PP * 4;   // 0.82 MB
    _Float16* n2inv = (_Float16*)ws;               ws += (size_t)BBATCH * LL * PP * 2;   // 0.41 MB
    _Float16* h1    = (_Float16*)ws;               ws += (size_t)BBATCH * LL * KG * 2;   // 8.19 MB
    _Float16* h2    = (_Float16*)ws;               ws += (size_t)BBATCH * LL * KG * 2;   // 8.19 MB
    _Float16* ksqt  = (_Float16*)ws;               ws += (size_t)640 * 8 * 2;            // 10 KB
    float*    part  = (float*)ws;                  // 2*64*200*16 f32 = 1.64 MB (total ~19.3 MB)

    prep_kernel<<<dim3(7, 2, BBATCH), 256, 0, stream>>>(sent1, sent2, kernel,
                                                        n1inv, n2inv, h1, h2, ksqt);

    const int lds_bytes = (112 * PS + 112 * PP) * 2;   // 77,056 B -> 2 blocks/CU
    hipFuncSetAttribute((const void*)maxsim_kernel,
                        hipFuncAttributeMaxDynamicSharedMemorySize, lds_bytes);
    maxsim_kernel<<<dim3(512, 1, 1), 256, lds_bytes, stream>>>(h1, h2, ksqt, n2inv, part);

    int nout = BBATCH * LL * PP;
    reduce_kernel<<<(nout + 255) / 256, 256, 0, stream>>>(part, n1inv, out);
}

// Round 5
// 178.312 us; speedup vs baseline: 1.7054x; 1.3194x over previous
//
#include <hip/hip_runtime.h>
#include <math.h>

#define BBATCH 64
#define LL 200
#define DD 300
#define PP 16
#define EPSV 1e-12f
#define KG 320          // global K-pad (10 chunks of 32)
#define PS 328          // maxsim LDS row stride in halfs (656 B: 4-bank row shift)
#define NCH 10
#define SRS 308         // prep LDS row stride in f32: 308 mod 32 = 12 -> 8-row groups hit all 32 banks

typedef _Float16 f16x8 __attribute__((ext_vector_type(8)));
typedef float f32x4v __attribute__((ext_vector_type(4)));

// ---------------- prep: norms + f16 conversion + ksq frag table --------------------------
// grid (7, 2, 64), block 256. 32 rows/block. which=0: h1 + n1inv(f32); which=1: h2 + n2inv(f16).
// (which==1, grp==6, b==0) also emits ksqt = f16(kp^2) in 16x16x32 A/B-frag layout.
__global__ __launch_bounds__(256) void prep_kernel(const float* __restrict__ s1,
                                                   const float* __restrict__ s2,
                                                   const float* __restrict__ kern,
                                                   float* __restrict__ n1inv,
                                                   _Float16* __restrict__ n2inv,
                                                   _Float16* __restrict__ h1,
                                                   _Float16* __restrict__ h2,
                                                   _Float16* __restrict__ ksqt) {
    const int grp   = blockIdx.x;   // 0..6 (32-row groups)
    const int which = blockIdx.y;
    const int b     = blockIdx.z;
    const float* s  = which ? s2 : s1;
    _Float16* hout  = which ? h2 : h1;
    const int r0    = grp * 32;
    const int t     = threadIdx.x;

    __shared__ float sr[32][SRS];    // 38.5 KB
    __shared__ float kq2[16][SRS];   // 19.25 KB  (total 57.75 KB -> 2 blocks/CU)

    // stage k^2 (squared once here)
    for (int idx = t; idx < 16 * 75; idx += 256) {
        int p = idx / 75, c4 = (idx - p * 75) * 4;
        float4 kv = *(const float4*)&kern[p * DD + c4];
        kv.x *= kv.x; kv.y *= kv.y; kv.z *= kv.z; kv.w *= kv.w;
        *(float4*)&kq2[p][c4] = kv;
    }
    // stage s rows (coalesced float4)
    for (int idx = t; idx < 32 * 75; idx += 256) {
        int r = idx / 75, c4 = (idx - r * 75) * 4;
        int row = r0 + r;
        float4 v = make_float4(0.f, 0.f, 0.f, 0.f);
        if (row < LL) v = *(const float4*)&s[((size_t)b * LL + row) * DD + c4];
        *(float4*)&sr[r][c4] = v;
    }
    // zero tails [300..307] so 8-wide f16 emit / frag gen can read freely
    {
        int r = t >> 3, cc = 300 + (t & 7);
        sr[r][cc] = 0.f;
        if (r < 16) kq2[r][cc] = 0.f;
    }
    __syncthreads();

    // norms: thread (r = t>>3, pq = t&7) computes p = pq and pq+8; conflict-free banks.
    {
        const int r = t >> 3, pq = t & 7;
        float acc0 = 0.f, acc1 = 0.f;
        for (int c4 = 0; c4 < 75; c4++) {
            float4 a  = *(const float4*)&sr[r][c4 * 4];
            float4 k0 = *(const float4*)&kq2[pq][c4 * 4];
            float4 k1 = *(const float4*)&kq2[pq + 8][c4 * 4];
            float x0 = a.x * a.x, x1 = a.y * a.y, x2 = a.z * a.z, x3 = a.w * a.w;
            acc0 += x0 * k0.x + x1 * k0.y + x2 * k0.z + x3 * k0.w;
            acc1 += x0 * k1.x + x1 * k1.y + x2 * k1.z + x3 * k1.w;
        }
        int row = r0 + r;
        if (row < LL) {
            float i0 = 1.0f / sqrtf(fmaxf(acc0, EPSV));
            float i1 = 1.0f / sqrtf(fmaxf(acc1, EPSV));
            if (which) {
                n2inv[((size_t)b * LL + row) * PP + pq]     = (_Float16)i0;
                n2inv[((size_t)b * LL + row) * PP + pq + 8] = (_Float16)i1;
            } else {
                n1inv[((size_t)b * LL + row) * PP + pq]     = i0;
                n1inv[((size_t)b * LL + row) * PP + pq + 8] = i1;
            }
        }
    }

    // emit f16 rows (row-major, K-padded to 320)
    for (int idx = t; idx < 32 * 40; idx += 256) {
        int r = idx / 40, e0 = (idx - r * 40) * 8;
        int row = r0 + r;
        if (row >= LL) continue;
        f16x8 h;
        if (e0 < 304) {
            float4 a = *(const float4*)&sr[r][e0];
            float4 d = *(const float4*)&sr[r][e0 + 4];
            h[0] = (_Float16)a.x; h[1] = (_Float16)a.y; h[2] = (_Float16)a.z; h[3] = (_Float16)a.w;
            h[4] = (_Float16)d.x; h[5] = (_Float16)d.y; h[6] = (_Float16)d.z; h[7] = (_Float16)d.w;
        } else {
#pragma unroll
            for (int e = 0; e < 8; e++) h[e] = (_Float16)0.f;
        }
        *(f16x8*)&hout[((size_t)b * LL + row) * KG + e0] = h;
    }

    // ksq frag table: ksqt[((ch*4+quad)*16+p)*8 + e] = f16(kp[p][ch*32+quad*8+e]^2)
    if (which == 1 && grp == 6 && b == 0) {
        for (int ent = t; ent < 640; ent += 256) {
            int ch = ent / 64, rem = ent - ch * 64;
            int quad = rem >> 4, p = rem & 15;
            int k0 = ch * 32 + quad * 8;
            f16x8 h;
            if (k0 < 304) {
                float4 a = *(const float4*)&kq2[p][k0];
                float4 d = *(const float4*)&kq2[p][k0 + 4];
                h[0] = (_Float16)(a.x); h[1] = (_Float16)(a.y);
                h[2] = (_Float16)(a.z); h[3] = (_Float16)(a.w);
                h[4] = (_Float16)(d.x); h[5] = (_Float16)(d.y);
                h[6] = (_Float16)(d.z); h[7] = (_Float16)(d.w);
            } else {
#pragma unroll
                for (int e = 0; e < 8; e++) h[e] = (_Float16)0.f;
            }
            *(f16x8*)&ksqt[(size_t)ent * 8] = h;
        }
    }
}

// ---------------- maxsim: 256-thr / 4-wave blocks, B-tile in LDS, A-frags in registers --
// EMPIRICAL register model (r0/r1/r3/r4): unified budget = 512 / waves_per_eu_min, split
// ~50:50 arch/acc. 512-thr blocks imply 2 waves/EU; (256,2) requests it -> 128 arch -> spill.
// ONLY (256,1) yields 256 arch (r0, no spill). Demand here ~216 total, so with (256,1) the
// allocator fits naturally; 2 blocks x 4 waves x <=256 = 2048 = full CU pool, and LDS 77 KB
// -> 2 blocks/CU -> 2 waves/SIMD WITHOUT requesting it.
// grid 512 = (b) x (iblk) x (pgrp) x (jblk). Each wave: 32 i-rows in regs (af, 80 VGPR).
// iblk0 rows 0-127, iblk1 rows 72-199 (overlap writes bit-identical, benign).
// B tile: 112 real j-rows (7 j-tiles), jt split 4+3 keeps acc at 64 VGPR.
// ksq folded into A side: 4 pk_muls feed up to 16 MFMAs per (ch, pass).
__global__ __launch_bounds__(256, 1) void maxsim_kernel(const _Float16* __restrict__ h1,
                                                        const _Float16* __restrict__ h2,
                                                        const _Float16* __restrict__ ksqt,
                                                        const _Float16* __restrict__ n2inv,
                                                        float* __restrict__ part) {
    extern __shared__ __align__(16) char smem[];
    _Float16* h2s = (_Float16*)smem;          // 112*PS halfs = 73,472 B
    _Float16* n2s = h2s + 112 * PS;           // 112*16 halfs =  3,584 B  (total 77,056)

    const int blk  = blockIdx.x;
    const int b    = blk & 63;
    const int v    = blk >> 6;                // 0..7
    const int iblk = v & 1;
    const int pgrp = (v >> 1) & 1;
    const int jblk = v >> 2;
    const int i0   = iblk ? 72 : 0;
    const int j0   = jblk ? 88 : 0;
    const int t    = threadIdx.x;

    const int lane = t & 63;
    const int w    = t >> 6;                  // 4 waves
    const int c    = lane & 15;
    const int quad = lane >> 4;
    const int ibase = i0 + w * 32;

    // A fragments: global -> registers (20 x b128; h1 is L2/L3-hot; latency overlaps staging)
    f16x8 af[2][NCH];
    {
        const _Float16* g1 = h1 + (size_t)b * LL * KG;
#pragma unroll
        for (int it = 0; it < 2; it++)
#pragma unroll
            for (int ch = 0; ch < NCH; ch++)
                af[it][ch] = *(const f16x8*)&g1[(size_t)(ibase + it * 16 + c) * KG + ch * 32 + quad * 8];
    }

    // stage B tile (112 rows, row-contiguous global -> padded-stride LDS) + n2
    {
        const _Float16* g2 = h2 + ((size_t)b * LL + j0) * KG;
        for (int idx = t; idx < 112 * 40; idx += 256) {
            int r = idx / 40, q = idx - r * 40;
            *(f16x8*)&h2s[r * PS + q * 8] = *(const f16x8*)&g2[(size_t)idx * 8];
        }
        const _Float16* gn = n2inv + ((size_t)b * LL + j0) * PP;
        for (int idx = t; idx < 224; idx += 256)
            *(f16x8*)&n2s[idx * 8] = *(const f16x8*)&gn[(size_t)idx * 8];
    }
    __syncthreads();

    for (int pp = 0; pp < 4; pp++) {
        const int p0 = pgrp * 8 + pp * 2;
        float rmax[2][2][4];                   // [pq][it][r] persists across the 2 jt-passes
#pragma unroll
        for (int pq = 0; pq < 2; pq++)
#pragma unroll
            for (int it = 0; it < 2; it++)
#pragma unroll
                for (int r = 0; r < 4; r++) rmax[pq][it][r] = -INFINITY;

#pragma unroll
        for (int pass = 0; pass < 2; pass++) {
            const int jt0 = pass * 4;
            const int jn  = pass ? 3 : 4;      // 7 j-tiles total, split 4+3
            f32x4v acc[2][2][4];               // [pq][it][jt] (64 VGPRs)
#pragma unroll
            for (int pq = 0; pq < 2; pq++)
#pragma unroll
                for (int it = 0; it < 2; it++)
#pragma unroll
                    for (int jt = 0; jt < 4; jt++) acc[pq][it][jt] = (f32x4v)0.f;

            f16x8 kq[2][2];
            kq[0][0] = *(const f16x8*)&ksqt[quad * 128 + p0 * 8];
            kq[0][1] = *(const f16x8*)&ksqt[quad * 128 + p0 * 8 + 8];
#pragma unroll
            for (int ch = 0; ch < NCH; ch++) {
                const int cur = ch & 1, nxt = cur ^ 1;
                if (ch < NCH - 1) {            // prefetch next chunk's ksq frags (L2-hot 10 KB)
                    kq[nxt][0] = *(const f16x8*)&ksqt[(ch + 1) * 512 + quad * 128 + p0 * 8];
                    kq[nxt][1] = *(const f16x8*)&ksqt[(ch + 1) * 512 + quad * 128 + p0 * 8 + 8];
                }
                // fold ksq into the A side: 4 pk_muls feed up to 16 MFMAs
                f16x8 sa00 = af[0][ch] * kq[cur][0];
                f16x8 sa10 = af[1][ch] * kq[cur][0];
                f16x8 sa01 = af[0][ch] * kq[cur][1];
                f16x8 sa11 = af[1][ch] * kq[cur][1];
#pragma unroll
                for (int jt = 0; jt < 4; jt++) {
                    if (jt < jn) {
                        f16x8 hb = *(const f16x8*)&h2s[((jt0 + jt) * 16 + c) * PS + ch * 32 + quad * 8];
                        acc[0][0][jt] = __builtin_amdgcn_mfma_f32_16x16x32_f16(sa00, hb, acc[0][0][jt], 0, 0, 0);
                        acc[0][1][jt] = __builtin_amdgcn_mfma_f32_16x16x32_f16(sa10, hb, acc[0][1][jt], 0, 0, 0);
                        acc[1][0][jt] = __builtin_amdgcn_mfma_f32_16x16x32_f16(sa01, hb, acc[1][0][jt], 0, 0, 0);
                        acc[1][1][jt] = __builtin_amdgcn_mfma_f32_16x16x32_f16(sa11, hb, acc[1][1][jt], 0, 0, 0);
                    }
                }
            }
            // fold this pass into rmax: scale cols by n2, max over j-tiles
#pragma unroll
            for (int pq = 0; pq < 2; pq++)
#pragma unroll
                for (int jt = 0; jt < 4; jt++) {
                    if (jt < jn) {
                        float n2 = (float)n2s[((jt0 + jt) * 16 + c) * PP + p0 + pq];
#pragma unroll
                        for (int it = 0; it < 2; it++)
#pragma unroll
                            for (int r = 0; r < 4; r++)
                                rmax[pq][it][r] = fmaxf(rmax[pq][it][r], acc[pq][it][jt][r] * n2);
                    }
                }
        }

        // reduce over j-col (lane bits 0..3) and write (C/D: col=lane&15=j, row=quad*4+r)
#pragma unroll
        for (int pq = 0; pq < 2; pq++) {
#pragma unroll
            for (int m = 1; m <= 8; m <<= 1)
#pragma unroll
                for (int it = 0; it < 2; it++)
#pragma unroll
                    for (int r = 0; r < 4; r++)
                        rmax[pq][it][r] = fmaxf(rmax[pq][it][r], __shfl_xor(rmax[pq][it][r], m));
            if (c == 0) {
#pragma unroll
                for (int it = 0; it < 2; it++)
#pragma unroll
                    for (int r = 0; r < 4; r++) {
                        int i = ibase + it * 16 + quad * 4 + r;   // < 200 by construction
                        part[((size_t)jblk * BBATCH + b) * (LL * PP) + (size_t)i * PP + p0 + pq] = rmax[pq][it][r];
                    }
            }
        }
    }
}

// ---------------- reduce: out = max(part0, part1) * n1inv --------------------------------
__global__ __launch_bounds__(256) void reduce_kernel(const float* __restrict__ part,
                                                     const float* __restrict__ n1inv,
                                                     float* __restrict__ out) {
    int tid = blockIdx.x * 256 + threadIdx.x;
    if (tid >= BBATCH * LL * PP) return;
    out[tid] = fmaxf(part[tid], part[(size_t)BBATCH * LL * PP + tid]) * n1inv[tid];
}

extern "C" void kernel_launch(void* const* d_in, const int* in_sizes, int n_in,
                              void* d_out, int out_size, void* d_ws, size_t ws_size,
                              hipStream_t stream) {
    const float* sent1  = (const float*)d_in[0];   // (64,200,300) f32
    const float* sent2  = (const float*)d_in[1];   // (64,200,300) f32
    const float* kernel = (const float*)d_in[2];   // (16,300)     f32
    float* out = (float*)d_out;                    // (64,200,16)  f32

    char* ws = (char*)d_ws;
    float*    n1inv = (float*)ws;                  ws += (size_t)BBATCH * LL * PP * 4;   // 0.82 MB
    _Float16* n2inv = (_Float16*)ws;               ws += (size_t)BBATCH * LL * PP * 2;   // 0.41 MB
    _Float16* h1    = (_Float16*)ws;               ws += (size_t)BBATCH * LL * KG * 2;   // 8.19 MB
    _Float16* h2    = (_Float16*)ws;               ws += (size_t)BBATCH * LL * KG * 2;   // 8.19 MB
    _Float16* ksqt  = (_Float16*)ws;               ws += (size_t)640 * 8 * 2;            // 10 KB
    float*    part  = (float*)ws;                  // 2*64*200*16 f32 = 1.64 MB (total ~19.3 MB)

    prep_kernel<<<dim3(7, 2, BBATCH), 256, 0, stream>>>(sent1, sent2, kernel,
                                                        n1inv, n2inv, h1, h2, ksqt);

    const int lds_bytes = (112 * PS + 112 * PP) * 2;   // 77,056 B -> 2 blocks/CU
    hipFuncSetAttribute((const void*)maxsim_kernel,
                        hipFuncAttributeMaxDynamicSharedMemorySize, lds_bytes);
    maxsim_kernel<<<dim3(512, 1, 1), 256, lds_bytes, stream>>>(h1, h2, ksqt, n2inv, part);

    int nout = BBATCH * LL * PP;
    reduce_kernel<<<(nout + 255) / 256, 256, 0, stream>>>(part, n1inv, out);
}

// Round 6
// 177.090 us; speedup vs baseline: 1.7171x; 1.0069x over previous
//
#include <hip/hip_runtime.h>
#include <math.h>

#define BBATCH 64
#define LL 200
#define DD 300
#define PP 16
#define EPSV 1e-12f
#define KG 320          // global K-pad (10 chunks of 32)
#define PS 328          // maxsim LDS row stride in halfs (656 B: 4-bank row shift)
#define NCH 10
#define SRS 308         // prep LDS row stride in f32: 308 mod 32 = 12 -> 8-row groups hit all 32 banks

typedef _Float16 f16x8 __attribute__((ext_vector_type(8)));
typedef float f32x4v __attribute__((ext_vector_type(4)));

// ---------------- prep: norms + f16 conversion + ksq frag table --------------------------
// grid (7, 2, 64), block 256. 32 rows/block. which=0: h1 + n1inv(f32); which=1: h2 + n2inv(f16).
// (which==1, grp==6, b==0) also emits ksqt = f16(kp^2) in 16x16x32 A/B-frag layout.
__global__ __launch_bounds__(256) void prep_kernel(const float* __restrict__ s1,
                                                   const float* __restrict__ s2,
                                                   const float* __restrict__ kern,
                                                   float* __restrict__ n1inv,
                                                   _Float16* __restrict__ n2inv,
                                                   _Float16* __restrict__ h1,
                                                   _Float16* __restrict__ h2,
                                                   _Float16* __restrict__ ksqt) {
    const int grp   = blockIdx.x;   // 0..6 (32-row groups)
    const int which = blockIdx.y;
    const int b     = blockIdx.z;
    const float* s  = which ? s2 : s1;
    _Float16* hout  = which ? h2 : h1;
    const int r0    = grp * 32;
    const int t     = threadIdx.x;

    __shared__ float sr[32][SRS];    // 38.5 KB
    __shared__ float kq2[16][SRS];   // 19.25 KB  (total 57.75 KB -> 2 blocks/CU)

    // stage k^2 (squared once here)
    for (int idx = t; idx < 16 * 75; idx += 256) {
        int p = idx / 75, c4 = (idx - p * 75) * 4;
        float4 kv = *(const float4*)&kern[p * DD + c4];
        kv.x *= kv.x; kv.y *= kv.y; kv.z *= kv.z; kv.w *= kv.w;
        *(float4*)&kq2[p][c4] = kv;
    }
    // stage s rows (coalesced float4)
    for (int idx = t; idx < 32 * 75; idx += 256) {
        int r = idx / 75, c4 = (idx - r * 75) * 4;
        int row = r0 + r;
        float4 v = make_float4(0.f, 0.f, 0.f, 0.f);
        if (row < LL) v = *(const float4*)&s[((size_t)b * LL + row) * DD + c4];
        *(float4*)&sr[r][c4] = v;
    }
    // zero tails [300..307] so 8-wide f16 emit / frag gen can read freely
    {
        int r = t >> 3, cc = 300 + (t & 7);
        sr[r][cc] = 0.f;
        if (r < 16) kq2[r][cc] = 0.f;
    }
    __syncthreads();

    // norms: thread (r = t>>3, pq = t&7) computes p = pq and pq+8; conflict-free banks.
    {
        const int r = t >> 3, pq = t & 7;
        float acc0 = 0.f, acc1 = 0.f;
        for (int c4 = 0; c4 < 75; c4++) {
            float4 a  = *(const float4*)&sr[r][c4 * 4];
            float4 k0 = *(const float4*)&kq2[pq][c4 * 4];
            float4 k1 = *(const float4*)&kq2[pq + 8][c4 * 4];
            float x0 = a.x * a.x, x1 = a.y * a.y, x2 = a.z * a.z, x3 = a.w * a.w;
            acc0 += x0 * k0.x + x1 * k0.y + x2 * k0.z + x3 * k0.w;
            acc1 += x0 * k1.x + x1 * k1.y + x2 * k1.z + x3 * k1.w;
        }
        int row = r0 + r;
        if (row < LL) {
            float i0 = 1.0f / sqrtf(fmaxf(acc0, EPSV));
            float i1 = 1.0f / sqrtf(fmaxf(acc1, EPSV));
            if (which) {
                n2inv[((size_t)b * LL + row) * PP + pq]     = (_Float16)i0;
                n2inv[((size_t)b * LL + row) * PP + pq + 8] = (_Float16)i1;
            } else {
                n1inv[((size_t)b * LL + row) * PP + pq]     = i0;
                n1inv[((size_t)b * LL + row) * PP + pq + 8] = i1;
            }
        }
    }

    // emit f16 rows (row-major, K-padded to 320)
    for (int idx = t; idx < 32 * 40; idx += 256) {
        int r = idx / 40, e0 = (idx - r * 40) * 8;
        int row = r0 + r;
        if (row >= LL) continue;
        f16x8 h;
        if (e0 < 304) {
            float4 a = *(const float4*)&sr[r][e0];
            float4 d = *(const float4*)&sr[r][e0 + 4];
            h[0] = (_Float16)a.x; h[1] = (_Float16)a.y; h[2] = (_Float16)a.z; h[3] = (_Float16)a.w;
            h[4] = (_Float16)d.x; h[5] = (_Float16)d.y; h[6] = (_Float16)d.z; h[7] = (_Float16)d.w;
        } else {
#pragma unroll
            for (int e = 0; e < 8; e++) h[e] = (_Float16)0.f;
        }
        *(f16x8*)&hout[((size_t)b * LL + row) * KG + e0] = h;
    }

    // ksq frag table: ksqt[((ch*4+quad)*16+p)*8 + e] = f16(kp[p][ch*32+quad*8+e]^2)
    if (which == 1 && grp == 6 && b == 0) {
        for (int ent = t; ent < 640; ent += 256) {
            int ch = ent / 64, rem = ent - ch * 64;
            int quad = rem >> 4, p = rem & 15;
            int k0 = ch * 32 + quad * 8;
            f16x8 h;
            if (k0 < 304) {
                float4 a = *(const float4*)&kq2[p][k0];
                float4 d = *(const float4*)&kq2[p][k0 + 4];
                h[0] = (_Float16)(a.x); h[1] = (_Float16)(a.y);
                h[2] = (_Float16)(a.z); h[3] = (_Float16)(a.w);
                h[4] = (_Float16)(d.x); h[5] = (_Float16)(d.y);
                h[6] = (_Float16)(d.z); h[7] = (_Float16)(d.w);
            } else {
#pragma unroll
                for (int e = 0; e < 8; e++) h[e] = (_Float16)0.f;
            }
            *(f16x8*)&ksqt[(size_t)ent * 8] = h;
        }
    }
}

// ---------------- maxsim: 256-thr / 4-wave blocks, B-tile in LDS, A-frags in registers --
// Register budget (r5 post-mortem: count VGPRs = 4B units, f16x8 = 4, f32x4v = 4!):
//   r5 had acc[2][2][4] = 128 VGPR -> total ~290 -> 1 wave/SIMD (Occ 10.4%).
// This version: j-tiles split {2,2,2,1} -> acc[2][2][2] = 64 VGPR. Total ~235-255 <= 256
// -> 2 waves/SIMD; LDS 77 KB -> 2 blocks/CU -> 8 waves/CU. hb amortization preserved
// (each B ds_read still feeds pq*it = 4 MFMAs; LDS pipe stays ~13 us total, not the wall).
// kq prefetch distance-2 (two 8-MFMA windows ~ L2 latency).
// grid 512 = (b) x (iblk) x (pgrp) x (jblk). Each wave: 32 i-rows in regs (af, 80 VGPR).
// iblk0 rows 0-127, iblk1 rows 72-199 (overlap writes bit-identical, benign).
__global__ __launch_bounds__(256, 1) void maxsim_kernel(const _Float16* __restrict__ h1,
                                                        const _Float16* __restrict__ h2,
                                                        const _Float16* __restrict__ ksqt,
                                                        const _Float16* __restrict__ n2inv,
                                                        float* __restrict__ part) {
    extern __shared__ __align__(16) char smem[];
    _Float16* h2s = (_Float16*)smem;          // 112*PS halfs = 73,472 B
    _Float16* n2s = h2s + 112 * PS;           // 112*16 halfs =  3,584 B  (total 77,056)

    const int blk  = blockIdx.x;
    const int b    = blk & 63;
    const int v    = blk >> 6;                // 0..7
    const int iblk = v & 1;
    const int pgrp = (v >> 1) & 1;
    const int jblk = v >> 2;
    const int i0   = iblk ? 72 : 0;
    const int j0   = jblk ? 88 : 0;
    const int t    = threadIdx.x;

    const int lane = t & 63;
    const int w    = t >> 6;                  // 4 waves
    const int c    = lane & 15;
    const int quad = lane >> 4;
    const int ibase = i0 + w * 32;

    // A fragments: global -> registers (20 x b128 = 80 VGPR; h1 is L2/L3-hot)
    f16x8 af[2][NCH];
    {
        const _Float16* g1 = h1 + (size_t)b * LL * KG;
#pragma unroll
        for (int it = 0; it < 2; it++)
#pragma unroll
            for (int ch = 0; ch < NCH; ch++)
                af[it][ch] = *(const f16x8*)&g1[(size_t)(ibase + it * 16 + c) * KG + ch * 32 + quad * 8];
    }

    // stage B tile (112 rows, row-contiguous global -> padded-stride LDS) + n2
    {
        const _Float16* g2 = h2 + ((size_t)b * LL + j0) * KG;
        for (int idx = t; idx < 112 * 40; idx += 256) {
            int r = idx / 40, q = idx - r * 40;
            *(f16x8*)&h2s[r * PS + q * 8] = *(const f16x8*)&g2[(size_t)idx * 8];
        }
        const _Float16* gn = n2inv + ((size_t)b * LL + j0) * PP;
        for (int idx = t; idx < 224; idx += 256)
            *(f16x8*)&n2s[idx * 8] = *(const f16x8*)&gn[(size_t)idx * 8];
    }
    __syncthreads();

    for (int pp = 0; pp < 4; pp++) {
        const int p0 = pgrp * 8 + pp * 2;
        float rmax[2][2][4];                   // [pq][it][r], 16 VGPR, persists across passes
#pragma unroll
        for (int pq = 0; pq < 2; pq++)
#pragma unroll
            for (int it = 0; it < 2; it++)
#pragma unroll
                for (int r = 0; r < 4; r++) rmax[pq][it][r] = -INFINITY;

#pragma unroll
        for (int pass = 0; pass < 4; pass++) {
            const int jt0 = pass * 2;
            const int jn  = (pass < 3) ? 2 : 1;   // 7 j-tiles split {2,2,2,1}
            f32x4v acc[2][2][2];                  // [pq][it][jt] = 64 VGPR
#pragma unroll
            for (int pq = 0; pq < 2; pq++)
#pragma unroll
                for (int it = 0; it < 2; it++)
#pragma unroll
                    for (int jt = 0; jt < 2; jt++) acc[pq][it][jt] = (f32x4v)0.f;

            // kq rotating buffer, prefetch distance 2 (L2-hot 10 KB table)
            f16x8 kq[2][2];
            kq[0][0] = *(const f16x8*)&ksqt[quad * 128 + p0 * 8];
            kq[0][1] = *(const f16x8*)&ksqt[quad * 128 + p0 * 8 + 8];
            kq[1][0] = *(const f16x8*)&ksqt[512 + quad * 128 + p0 * 8];
            kq[1][1] = *(const f16x8*)&ksqt[512 + quad * 128 + p0 * 8 + 8];
#pragma unroll
            for (int ch = 0; ch < NCH; ch++) {
                const int cur = ch & 1;
                // fold ksq into the A side: 4 pk_muls feed up to 8 MFMAs
                f16x8 sa00 = af[0][ch] * kq[cur][0];
                f16x8 sa10 = af[1][ch] * kq[cur][0];
                f16x8 sa01 = af[0][ch] * kq[cur][1];
                f16x8 sa11 = af[1][ch] * kq[cur][1];
                if (ch < NCH - 2) {            // refill consumed slot for ch+2
                    kq[cur][0] = *(const f16x8*)&ksqt[(ch + 2) * 512 + quad * 128 + p0 * 8];
                    kq[cur][1] = *(const f16x8*)&ksqt[(ch + 2) * 512 + quad * 128 + p0 * 8 + 8];
                }
#pragma unroll
                for (int jt = 0; jt < 2; jt++) {
                    if (jt < jn) {
                        f16x8 hb = *(const f16x8*)&h2s[((jt0 + jt) * 16 + c) * PS + ch * 32 + quad * 8];
                        acc[0][0][jt] = __builtin_amdgcn_mfma_f32_16x16x32_f16(sa00, hb, acc[0][0][jt], 0, 0, 0);
                        acc[0][1][jt] = __builtin_amdgcn_mfma_f32_16x16x32_f16(sa10, hb, acc[0][1][jt], 0, 0, 0);
                        acc[1][0][jt] = __builtin_amdgcn_mfma_f32_16x16x32_f16(sa01, hb, acc[1][0][jt], 0, 0, 0);
                        acc[1][1][jt] = __builtin_amdgcn_mfma_f32_16x16x32_f16(sa11, hb, acc[1][1][jt], 0, 0, 0);
                    }
                }
            }
            // fold this pass into rmax: scale cols by n2, max over j-tiles
#pragma unroll
            for (int pq = 0; pq < 2; pq++)
#pragma unroll
                for (int jt = 0; jt < 2; jt++) {
                    if (jt < jn) {
                        float n2 = (float)n2s[((jt0 + jt) * 16 + c) * PP + p0 + pq];
#pragma unroll
                        for (int it = 0; it < 2; it++)
#pragma unroll
                            for (int r = 0; r < 4; r++)
                                rmax[pq][it][r] = fmaxf(rmax[pq][it][r], acc[pq][it][jt][r] * n2);
                    }
                }
        }

        // reduce over j-col (lane bits 0..3) and write (C/D: col=lane&15=j, row=quad*4+r)
#pragma unroll
        for (int pq = 0; pq < 2; pq++) {
#pragma unroll
            for (int m = 1; m <= 8; m <<= 1)
#pragma unroll
                for (int it = 0; it < 2; it++)
#pragma unroll
                    for (int r = 0; r < 4; r++)
                        rmax[pq][it][r] = fmaxf(rmax[pq][it][r], __shfl_xor(rmax[pq][it][r], m));
            if (c == 0) {
#pragma unroll
                for (int it = 0; it < 2; it++)
#pragma unroll
                    for (int r = 0; r < 4; r++) {
                        int i = ibase + it * 16 + quad * 4 + r;   // < 200 by construction
                        part[((size_t)jblk * BBATCH + b) * (LL * PP) + (size_t)i * PP + p0 + pq] = rmax[pq][it][r];
                    }
            }
        }
    }
}

// ---------------- reduce: out = max(part0, part1) * n1inv --------------------------------
__global__ __launch_bounds__(256) void reduce_kernel(const float* __restrict__ part,
                                                     const float* __restrict__ n1inv,
                                                     float* __restrict__ out) {
    int tid = blockIdx.x * 256 + threadIdx.x;
    if (tid >= BBATCH * LL * PP) return;
    out[tid] = fmaxf(part[tid], part[(size_t)BBATCH * LL * PP + tid]) * n1inv[tid];
}

extern "C" void kernel_launch(void* const* d_in, const int* in_sizes, int n_in,
                              void* d_out, int out_size, void* d_ws, size_t ws_size,
                              hipStream_t stream) {
    const float* sent1  = (const float*)d_in[0];   // (64,200,300) f32
    const float* sent2  = (const float*)d_in[1];   // (64,200,300) f32
    const float* kernel = (const float*)d_in[2];   // (16,300)     f32
    float* out = (float*)d_out;                    // (64,200,16)  f32

    char* ws = (char*)d_ws;
    float*    n1inv = (float*)ws;                  ws += (size_t)BBATCH * LL * PP * 4;   // 0.82 MB
    _Float16* n2inv = (_Float16*)ws;               ws += (size_t)BBATCH * LL * PP * 2;   // 0.41 MB
    _Float16* h1    = (_Float16*)ws;               ws += (size_t)BBATCH * LL * KG * 2;   // 8.19 MB
    _Float16* h2    = (_Float16*)ws;               ws += (size_t)BBATCH * LL * KG * 2;   // 8.19 MB
    _Float16* ksqt  = (_Float16*)ws;               ws += (size_t)640 * 8 * 2;            // 10 KB
    float*    part  = (float*)ws;                  // 2*64*200*16 f32 = 1.64 MB (total ~19.3 MB)

    prep_kernel<<<dim3(7, 2, BBATCH), 256, 0, stream>>>(sent1, sent2, kernel,
                                                        n1inv, n2inv, h1, h2, ksqt);

    const int lds_bytes = (112 * PS + 112 * PP) * 2;   // 77,056 B -> 2 blocks/CU
    hipFuncSetAttribute((const void*)maxsim_kernel,
                        hipFuncAttributeMaxDynamicSharedMemorySize, lds_bytes);
    maxsim_kernel<<<dim3(512, 1, 1), 256, lds_bytes, stream>>>(h1, h2, ksqt, n2inv, part);

    int nout = BBATCH * LL * PP;
    reduce_kernel<<<(nout + 255) / 256, 256, 0, stream>>>(part, n1inv, out);
}